// Round 1
// baseline (137.593 us; speedup 1.0000x reference)
//
#include <hip/hip_runtime.h>
#include <stdint.h>

using ushort8 = __attribute__((ext_vector_type(8))) unsigned short;
using bf16x8  = __attribute__((ext_vector_type(8))) __bf16;
using f32x16  = __attribute__((ext_vector_type(16))) float;

#define AS1 __attribute__((address_space(1)))
#define AS3 __attribute__((address_space(3)))

__device__ __forceinline__ unsigned short f2bf(float x){
  uint32_t u = __builtin_bit_cast(uint32_t, x);
  u = (u + 0x7FFFu + ((u >> 16) & 1u)) >> 16;   // RNE
  return (unsigned short)u;
}
__device__ __forceinline__ float bf2f(unsigned short b){
  uint32_t u = ((uint32_t)b) << 16;
  return __builtin_bit_cast(float, u);
}

// Pre-pass: 129 step-images of 128x128 bf16, pre-swizzled for bank-conflict-free
// ds_read_b128.  Step s<128: A[p][c] = W[(s*128+p)*128 + c]; step 128: A[p][i] = b[i*128+p].
// Stored element q at row p holds c = q ^ ((p&7)<<3).
__global__ void prep_wb(const float* __restrict__ W, const float* __restrict__ bias,
                        unsigned short* __restrict__ Wb){
  int e = blockIdx.x * 256 + threadIdx.x;
  if (e >= 129 * 16384) return;
  int s   = e >> 14;
  int rem = e & 16383;
  int p   = rem >> 7;
  int q   = rem & 127;
  int c   = q ^ ((p & 7) << 3);
  float v = (s < 128) ? W[(s << 14) + (p << 7) + c] : bias[(c << 7) + p];
  Wb[e] = f2bf(v);
}

__device__ __forceinline__ f32x16 mfma16(bf16x8 a, bf16x8 b, f32x16 c){
  return __builtin_amdgcn_mfma_f32_32x32x16_bf16(a, b, c, 0, 0, 0);
}

__device__ __forceinline__ bf16x8 cvt8(const float* p){
  ushort8 v;
  #pragma unroll
  for (int j = 0; j < 8; ++j) v[j] = f2bf(p[j]);
  return __builtin_bit_cast(bf16x8, v);
}

// WG: 512 threads (8 waves), owns all 128 p x 128 tokens.
// Wave (pt = wv>>1, tw = wv&1): 32p x 64t (two 32x32 MFMA col-tiles).
// LDS: [0,64K) W double-buffer (2x32KB), [64K,96K) imgT bf16 [i][t_local].
// Epilogue reuses [0,66K) as f32 [t][129] for LayerNorm.
__global__ __launch_bounds__(512, 2)
void dynmlp(const float* __restrict__ img, const float* __restrict__ loc,
            const unsigned short* __restrict__ Wb,
            const float* __restrict__ gamma, const float* __restrict__ beta,
            float* __restrict__ out){
  __shared__ __align__(16) char smem[98304];
  unsigned short* ldsImgT = (unsigned short*)(smem + 65536);
  float* ldsY = (float*)smem;

  const int tid    = threadIdx.x;
  const int lane   = tid & 63;
  const int wv     = tid >> 6;
  const int p_base = (wv >> 1) * 32;
  const int t_off  = (wv & 1) * 64;
  const int t_base = blockIdx.x * 128;
  const int l31    = lane & 31;
  const int lg     = lane >> 5;

  // ---- one-time: transpose img tile into LDS as bf16 [i][t_local] ----
  for (int e = tid; e < 16384; e += 512){
    int tl = e >> 7, i = e & 127;
    ldsImgT[i * 128 + tl] = f2bf(img[(t_base + tl) * 128 + i]);
  }

  // ---- one-time: register-stationary B-fragments ----
  // B[k=c][n=t]: lane holds col t = l31 (+tile), k = cc*16 + 8*lg + j  (j=0..7)
  bf16x8 bfr[2][8];   // loc  (main K-loop)
  bf16x8 bimg[2][8];  // img  (bias step)
  #pragma unroll
  for (int tt = 0; tt < 2; ++tt){
    int t = t_base + t_off + tt * 32 + l31;
    #pragma unroll
    for (int cc = 0; cc < 8; ++cc){
      int c0 = cc * 16 + 8 * lg;
      bfr[tt][cc]  = cvt8(&loc[t * 128 + c0]);
      bimg[tt][cc] = cvt8(&img[t * 128 + c0]);
    }
  }

  // ---- A-fragment LDS byte offsets (step-invariant; buffer base added later) ----
  // A[m=p][k=c]: lane holds row p = p_base + l31, k = cc*16 + 8*lg + j
  int aoff[8];
  {
    int row = p_base + l31;
    int sw  = (row & 7) << 4;
    #pragma unroll
    for (int cc = 0; cc < 8; ++cc)
      aoff[cc] = row * 256 + ((cc * 32 + 16 * lg) ^ sw);
  }

  #define STAGE(step, buf) do { \
    const char* _g = ((const char*)Wb) + (size_t)(step) * 32768 + tid * 16; \
    char* _l = smem + (buf) * 32768 + tid * 16; \
    __builtin_amdgcn_global_load_lds((const AS1 uint32_t*)(_g),         (AS3 uint32_t*)(_l),         16, 0, 0); \
    __builtin_amdgcn_global_load_lds((const AS1 uint32_t*)(_g + 8192),  (AS3 uint32_t*)(_l + 8192),  16, 0, 0); \
    __builtin_amdgcn_global_load_lds((const AS1 uint32_t*)(_g + 16384), (AS3 uint32_t*)(_l + 16384), 16, 0, 0); \
    __builtin_amdgcn_global_load_lds((const AS1 uint32_t*)(_g + 24576), (AS3 uint32_t*)(_l + 24576), 16, 0, 0); \
  } while (0)

  // ---- bias step (image 128) into buf0 ----
  STAGE(128, 0);
  __syncthreads();

  f32x16 acc0 = {}; f32x16 acc1 = {};
  STAGE(0, 1);                       // prefetch step 0 while computing bias
  #pragma unroll
  for (int cc = 0; cc < 8; ++cc){
    bf16x8 a = *(const bf16x8*)(smem + aoff[cc]);
    acc0 = mfma16(a, bimg[0][cc], acc0);
    acc1 = mfma16(a, bimg[1][cc], acc1);
  }
  __syncthreads();

  // ---- main K-loop: 128 steps over i ----
  const unsigned short* imgRow = ldsImgT + t_off + l31;
  #pragma unroll 2
  for (int ki = 0; ki < 128; ++ki){
    if (ki < 127) STAGE(ki + 1, ki & 1);          // prefetch next into free buf
    float s0 = bf2f(imgRow[ki * 128]);            // img[t, ki] for this lane's col
    float s1 = bf2f(imgRow[ki * 128 + 32]);
    const char* bufp = smem + ((ki + 1) & 1) * 32768;
    f32x16 S = {}; f32x16 T = {};
    #pragma unroll
    for (int cc = 0; cc < 8; ++cc){
      bf16x8 a = *(const bf16x8*)(bufp + aoff[cc]);
      S = mfma16(a, bfr[0][cc], S);
      T = mfma16(a, bfr[1][cc], T);
    }
    acc0 += S * s0;                               // fold img[t,ki] on VALU pipe
    acc1 += T * s1;
    __syncthreads();
  }

  // ---- epilogue: acc -> LDS [t][129] f32 ----
  // C/D layout: col = l31 (t), row = (r&3) + 8*(r>>2) + 4*lg (p)
  #pragma unroll
  for (int tt = 0; tt < 2; ++tt){
    int t_l = t_off + tt * 32 + l31;
    #pragma unroll
    for (int r = 0; r < 16; ++r){
      int p = p_base + (r & 3) + 8 * (r >> 2) + 4 * lg;
      ldsY[t_l * 129 + p] = tt ? acc1[r] : acc0[r];
    }
  }
  __syncthreads();

  // ---- LayerNorm + ReLU: wave wv handles tokens [wv*16, wv*16+16) ----
  float g0  = gamma[lane], g1 = gamma[lane + 64];
  float be0 = beta[lane],  be1 = beta[lane + 64];
  #pragma unroll 1
  for (int k = 0; k < 16; ++k){
    int t_l = wv * 16 + k;
    float y0 = ldsY[t_l * 129 + lane];
    float y1 = ldsY[t_l * 129 + 64 + lane];
    float s = y0 + y1, sq = y0 * y0 + y1 * y1;
    #pragma unroll
    for (int m = 32; m >= 1; m >>= 1){
      s  += __shfl_xor(s, m, 64);
      sq += __shfl_xor(sq, m, 64);
    }
    float mean = s * (1.0f / 128.0f);
    float var  = sq * (1.0f / 128.0f) - mean * mean;
    float rs   = rsqrtf(var + 1e-5f);
    float o0 = fmaxf((y0 - mean) * rs * g0 + be0, 0.0f);
    float o1 = fmaxf((y1 - mean) * rs * g1 + be1, 0.0f);
    int t = t_base + t_l;
    out[t * 128 + lane]      = o0;
    out[t * 128 + 64 + lane] = o1;
  }
}

extern "C" void kernel_launch(void* const* d_in, const int* in_sizes, int n_in,
                              void* d_out, int out_size, void* d_ws, size_t ws_size,
                              hipStream_t stream){
  const float* img   = (const float*)d_in[0];
  const float* loc   = (const float*)d_in[1];
  const float* W     = (const float*)d_in[2];
  const float* bias  = (const float*)d_in[3];
  const float* gamma = (const float*)d_in[4];
  const float* beta  = (const float*)d_in[5];
  float* out = (float*)d_out;
  unsigned short* Wb = (unsigned short*)d_ws;   // 129*16384*2 = 4,227,072 B

  prep_wb<<<(129 * 16384) / 256, 256, 0, stream>>>(W, bias, Wb);
  dynmlp<<<128, 512, 0, stream>>>(img, loc, Wb, gamma, beta, out);
}

// Round 2
// 101.386 us; speedup vs baseline: 1.3571x; 1.3571x over previous
//
#include <hip/hip_runtime.h>
#include <stdint.h>

using ushort8 = __attribute__((ext_vector_type(8))) unsigned short;
using bf16x8  = __attribute__((ext_vector_type(8))) __bf16;
using f32x16  = __attribute__((ext_vector_type(16))) float;

#define AS1 __attribute__((address_space(1)))
#define AS3 __attribute__((address_space(3)))

__device__ __forceinline__ unsigned short f2bf(float x){
  uint32_t u = __builtin_bit_cast(uint32_t, x);
  u = (u + 0x7FFFu + ((u >> 16) & 1u)) >> 16;   // RNE
  return (unsigned short)u;
}
__device__ __forceinline__ float bf2f(unsigned short b){
  uint32_t u = ((uint32_t)b) << 16;
  return __builtin_bit_cast(float, u);
}

// Pre-pass: 129 step-images of 128x128 bf16, pre-swizzled for bank-conflict-free
// ds_read_b128.  Step s<128: A[p][c] = W[(s*128+p)*128 + c]; step 128: A[p][i] = b[i*128+p].
// Stored element q at row p holds c = q ^ ((p&7)<<3).
__global__ void prep_wb(const float* __restrict__ W, const float* __restrict__ bias,
                        unsigned short* __restrict__ Wb){
  int e = blockIdx.x * 256 + threadIdx.x;
  if (e >= 129 * 16384) return;
  int s   = e >> 14;
  int rem = e & 16383;
  int p   = rem >> 7;
  int q   = rem & 127;
  int c   = q ^ ((p & 7) << 3);
  float v = (s < 128) ? W[(s << 14) + (p << 7) + c] : bias[(c << 7) + p];
  Wb[e] = f2bf(v);
}

__device__ __forceinline__ f32x16 mfma16(bf16x8 a, bf16x8 b, f32x16 c){
  return __builtin_amdgcn_mfma_f32_32x32x16_bf16(a, b, c, 0, 0, 0);
}

__device__ __forceinline__ bf16x8 cvt8(const float* p){
  ushort8 v;
  #pragma unroll
  for (int j = 0; j < 8; ++j) v[j] = f2bf(p[j]);
  return __builtin_bit_cast(bf16x8, v);
}

// WG: 512 threads (8 waves), owns 128 p x 64 tokens. Grid = 256 WGs (all CUs).
// Wave (wv>>1 = p-tile, wv&1 = t-tile): 32p x 32t, one MFMA chain per step.
// LDS: [0,96K) W triple-buffer ring (3x32KB), [96K,112K) imgT bf16 (XOR-swizzled).
// Epilogue reuses [0,33K) as f32 [t][129] for LayerNorm.
__global__ __launch_bounds__(512, 2)
void dynmlp(const float* __restrict__ img, const float* __restrict__ loc,
            const unsigned short* __restrict__ Wb,
            const float* __restrict__ gamma, const float* __restrict__ beta,
            float* __restrict__ out){
  __shared__ __align__(16) char smem[114688];
  unsigned short* ldsImgT = (unsigned short*)(smem + 98304); // [128 i][64 t] u16, swizzled
  float* ldsY = (float*)smem;                                 // [64 t][129] f32

  const int tid    = threadIdx.x;
  const int lane   = tid & 63;
  const int wv     = tid >> 6;
  const int p_base = (wv >> 1) * 32;
  const int t_off  = (wv & 1) * 32;
  const int t_base = blockIdx.x * 64;
  const int l31    = lane & 31;
  const int lg     = lane >> 5;

  #define STAGE(step, buf) do { \
    const char* _g = ((const char*)Wb) + (size_t)(step) * 32768 + tid * 16; \
    char* _l = smem + (buf) * 32768 + tid * 16; \
    __builtin_amdgcn_global_load_lds((const AS1 uint32_t*)(_g),         (AS3 uint32_t*)(_l),         16, 0, 0); \
    __builtin_amdgcn_global_load_lds((const AS1 uint32_t*)(_g + 8192),  (AS3 uint32_t*)(_l + 8192),  16, 0, 0); \
    __builtin_amdgcn_global_load_lds((const AS1 uint32_t*)(_g + 16384), (AS3 uint32_t*)(_l + 16384), 16, 0, 0); \
    __builtin_amdgcn_global_load_lds((const AS1 uint32_t*)(_g + 24576), (AS3 uint32_t*)(_l + 24576), 16, 0, 0); \
  } while (0)

  // ---- prologue: start pipeline, fill imgT, build register-stationary frags ----
  STAGE(0, 0);
  STAGE(1, 1);

  // imgT[i][t] at u16 index i*64 + (t ^ ((i&31)<<1)) : conflict-free writes AND reads.
  for (int e = tid; e < 8192; e += 512){
    int tl = e >> 7, i = e & 127;
    ldsImgT[i * 64 + (tl ^ ((i & 31) << 1))] = f2bf(img[(size_t)(t_base + tl) * 128 + i]);
  }

  // B[k=c][n=t]: lane holds col t = t_base + t_off + l31, k = cc*16 + 8*lg + j (j=0..7)
  bf16x8 bfr[8];   // loc  (main K-loop, register-stationary)
  bf16x8 bimg[8];  // img  (bias step)
  {
    int t = t_base + t_off + l31;
    #pragma unroll
    for (int cc = 0; cc < 8; ++cc){
      int c0 = cc * 16 + 8 * lg;
      bfr[cc]  = cvt8(&loc[t * 128 + c0]);
      bimg[cc] = cvt8(&img[t * 128 + c0]);
    }
  }

  // A-frag LDS byte offsets (step-invariant): row p = p_base + l31, k = cc*16+8*lg+j
  int aoff[8];
  {
    int row = p_base + l31;
    int sw  = (row & 7) << 4;
    #pragma unroll
    for (int cc = 0; cc < 8; ++cc)
      aoff[cc] = row * 256 + ((cc * 32 + 16 * lg) ^ sw);
  }

  __syncthreads();   // one-time full drain: imgT + STAGE(0),STAGE(1) ready

  // ---- main K-loop: 128 steps, 3-buffer ring, prefetch distance 2, counted vmcnt ----
  const int img_ix = t_off + l31;
  f32x16 acc = {};
  #pragma unroll 3
  for (int ki = 0; ki < 128; ++ki){
    if (ki + 2 <= 128) STAGE(ki + 2, (ki + 2) % 3);
    const char* bufp = smem + (ki % 3) * 32768;
    f32x16 S = {}; f32x16 S2 = {};
    __builtin_amdgcn_s_setprio(1);
    #pragma unroll
    for (int cc = 0; cc < 4; ++cc){
      bf16x8 a0 = *(const bf16x8*)(bufp + aoff[cc]);
      bf16x8 a1 = *(const bf16x8*)(bufp + aoff[cc + 4]);
      S  = mfma16(a0, bfr[cc],     S);
      S2 = mfma16(a1, bfr[cc + 4], S2);
    }
    __builtin_amdgcn_s_setprio(0);
    float s0 = bf2f(ldsImgT[(ki << 6) + (img_ix ^ ((ki & 31) << 1))]);
    acc += (S + S2) * s0;
    // keep newest STAGE (4 loads) in flight across the barrier; retire all ds_reads
    asm volatile("s_waitcnt vmcnt(4) lgkmcnt(0)" ::: "memory");
    __builtin_amdgcn_s_barrier();
  }

  // ---- bias step (step 128, buf 2): acc += b-contribution (no scale) ----
  asm volatile("s_waitcnt vmcnt(0)" ::: "memory");
  __builtin_amdgcn_s_barrier();
  {
    const char* bufp = smem + 2 * 32768;
    f32x16 S = {}; f32x16 S2 = {};
    #pragma unroll
    for (int cc = 0; cc < 4; ++cc){
      bf16x8 a0 = *(const bf16x8*)(bufp + aoff[cc]);
      bf16x8 a1 = *(const bf16x8*)(bufp + aoff[cc + 4]);
      S  = mfma16(a0, bimg[cc],     S);
      S2 = mfma16(a1, bimg[cc + 4], S2);
    }
    acc += S + S2;
  }

  // ---- epilogue: acc -> LDS [t][129] f32 (disjoint from buf2 being read above) ----
  // C/D layout: col = l31 (t), row = (r&3) + 8*(r>>2) + 4*lg (p)
  {
    int t_l = t_off + l31;
    #pragma unroll
    for (int r = 0; r < 16; ++r){
      int p = p_base + (r & 3) + 8 * (r >> 2) + 4 * lg;
      ldsY[t_l * 129 + p] = acc[r];
    }
  }
  __syncthreads();

  // ---- LayerNorm + ReLU: wave wv handles tokens [wv*8, wv*8+8) ----
  float g0  = gamma[lane], g1 = gamma[lane + 64];
  float be0 = beta[lane],  be1 = beta[lane + 64];
  #pragma unroll 1
  for (int k = 0; k < 8; ++k){
    int t_l = wv * 8 + k;
    float y0 = ldsY[t_l * 129 + lane];
    float y1 = ldsY[t_l * 129 + 64 + lane];
    float s = y0 + y1, sq = y0 * y0 + y1 * y1;
    #pragma unroll
    for (int m = 32; m >= 1; m >>= 1){
      s  += __shfl_xor(s, m, 64);
      sq += __shfl_xor(sq, m, 64);
    }
    float mean = s * (1.0f / 128.0f);
    float var  = sq * (1.0f / 128.0f) - mean * mean;
    float rs   = rsqrtf(var + 1e-5f);
    float o0 = fmaxf((y0 - mean) * rs * g0 + be0, 0.0f);
    float o1 = fmaxf((y1 - mean) * rs * g1 + be1, 0.0f);
    int t = t_base + t_l;
    out[t * 128 + lane]      = o0;
    out[t * 128 + 64 + lane] = o1;
  }
}

extern "C" void kernel_launch(void* const* d_in, const int* in_sizes, int n_in,
                              void* d_out, int out_size, void* d_ws, size_t ws_size,
                              hipStream_t stream){
  const float* img   = (const float*)d_in[0];
  const float* loc   = (const float*)d_in[1];
  const float* W     = (const float*)d_in[2];
  const float* bias  = (const float*)d_in[3];
  const float* gamma = (const float*)d_in[4];
  const float* beta  = (const float*)d_in[5];
  float* out = (float*)d_out;
  unsigned short* Wb = (unsigned short*)d_ws;   // 129*16384*2 = 4,227,072 B

  prep_wb<<<(129 * 16384) / 256, 256, 0, stream>>>(W, bias, Wb);
  dynmlp<<<256, 512, 0, stream>>>(img, loc, Wb, gamma, beta, out);
}

// Round 3
// 95.702 us; speedup vs baseline: 1.4377x; 1.0594x over previous
//
#include <hip/hip_runtime.h>
#include <stdint.h>

using ushort8 = __attribute__((ext_vector_type(8))) unsigned short;
using bf16x8  = __attribute__((ext_vector_type(8))) __bf16;
using f32x16  = __attribute__((ext_vector_type(16))) float;

#define AS1 __attribute__((address_space(1)))
#define AS3 __attribute__((address_space(3)))

__device__ __forceinline__ unsigned short f2bf(float x){
  uint32_t u = __builtin_bit_cast(uint32_t, x);
  u = (u + 0x7FFFu + ((u >> 16) & 1u)) >> 16;   // RNE
  return (unsigned short)u;
}
__device__ __forceinline__ float bf2f(unsigned short b){
  uint32_t u = ((uint32_t)b) << 16;
  return __builtin_bit_cast(float, u);
}

__device__ __forceinline__ f32x16 mfma16(bf16x8 a, bf16x8 b, f32x16 c){
  return __builtin_amdgcn_mfma_f32_32x32x16_bf16(a, b, c, 0, 0, 0);
}

__device__ __forceinline__ bf16x8 cvt8(const float* p){
  ushort8 v;
  #pragma unroll
  for (int j = 0; j < 8; ++j) v[j] = f2bf(p[j]);
  return __builtin_bit_cast(bf16x8, v);
}

// Pre-pass: Wb2[s][pt][ch][r][w][8] bf16, plain order (permutation happens at
// stage time via per-lane global addresses). s=0..127: W step images
// A[p][c] = W[(s*128+p)*128+c]; s=128: bias image A[p][i] = b[i*128+p].
// p = pt*32+r, c = ch*64 + w*8 + j.
__global__ void prep_wb2(const float* __restrict__ W, const float* __restrict__ bias,
                         unsigned short* __restrict__ Wb2){
  int e = blockIdx.x * 256 + threadIdx.x;
  if (e >= 129 * 16384) return;
  int jj = e & 7, w = (e >> 3) & 7, r = (e >> 6) & 31;
  int ch = (e >> 11) & 1, pt = (e >> 12) & 3, s = e >> 14;
  int p = pt * 32 + r, c = ch * 64 + w * 8 + jj;
  float v = (s < 128) ? W[(s << 14) + (p << 7) + c] : bias[(c << 7) + p];
  Wb2[e] = f2bf(v);
}

// dynmlp: grid 256 = 128 token-tiles x 2 K-halves. 512 threads = 8 waves
// = 4 p-tiles x 2 c-halves. Wave tile: 32p x 128t (F=4 frags) x 64c.
// Each wave stages its OWN 4KB W-slice (private 3-buffer ring) -> NO barriers
// in the 64-step main loop; per-wave counted vmcnt only.
// LDS: [0,96K) 8 x 12KB private rings, [96K,112K) imgT [64 s][128 t] bf16.
// Epilogue reuses [0,66K) as ldsY [128t][129p] f32 to combine c-halves.
__global__ __launch_bounds__(512, 2)
void dynmlp(const float* __restrict__ img, const float* __restrict__ loc,
            const unsigned short* __restrict__ Wb2, float* __restrict__ part){
  __shared__ __align__(16) char smem[114688];
  unsigned short* imgT = (unsigned short*)(smem + 98304);
  float* ldsY = (float*)smem;

  const int tid = threadIdx.x, lane = tid & 63, wv = tid >> 6;
  const int pt = wv >> 1, ch = wv & 1;
  const int tt = blockIdx.x >> 1, h = blockIdx.x & 1;
  const int l31 = lane & 31, lg = lane >> 5;
  const int t0 = tt * 128;

  // stage source byte-offsets within a 4KB slice (uniform-quadruple swizzle):
  // LDS[r][w] = G[r][w ^ (r&7)]
  int goff[4];
  #pragma unroll
  for (int j = 0; j < 4; ++j){
    int slot = j * 64 + lane, r = slot >> 3, w = slot & 7;
    goff[j] = (r * 8 + (w ^ (r & 7))) * 16;
  }
  const char* slice0 = (const char*)Wb2 + (pt * 2 + ch) * 4096;
  char* ringb = smem + wv * 12288;

  auto STG = [&](int step, int buf){
    const char* g = slice0 + (size_t)step * 32768;
    char* l = ringb + buf * 4096 + (lane << 4);
    #pragma unroll
    for (int j = 0; j < 4; ++j)
      __builtin_amdgcn_global_load_lds((const AS1 uint32_t*)(g + goff[j]),
                                       (AS3 uint32_t*)(l + j * 1024), 16, 0, 0);
  };

  STG(h * 64 + 0, 0);
  STG(h * 64 + 1, 1);

  // imgT fill: [s][t], i = h*64+s  (one-time, cooperative)
  for (int e = tid; e < 2048; e += 512){
    int tl = e >> 4, iq = e & 15;
    float4 v = *(const float4*)&img[(size_t)(t0 + tl) * 128 + h * 64 + iq * 4];
    int a = iq * 4 * 128 + tl;
    imgT[a]       = f2bf(v.x);
    imgT[a + 128] = f2bf(v.y);
    imgT[a + 256] = f2bf(v.z);
    imgT[a + 384] = f2bf(v.w);
  }

  // register-stationary B-frags: loc, this wave's c-half only
  bf16x8 bfr[4][4];
  #pragma unroll
  for (int f = 0; f < 4; ++f){
    int t = t0 + f * 32 + l31;
    #pragma unroll
    for (int cc = 0; cc < 4; ++cc)
      bfr[f][cc] = cvt8(&loc[(size_t)t * 128 + ch * 64 + cc * 16 + lg * 8]);
  }

  // A-frag byte offsets within a ring buffer
  int aoff[4];
  #pragma unroll
  for (int cc = 0; cc < 4; ++cc)
    aoff[cc] = (l31 * 8 + ((cc * 2 + lg) ^ (l31 & 7))) * 16;

  __syncthreads();   // imgT ready (only barrier before epilogue)

  f32x16 acc[4] = {{}, {}, {}, {}};
  const unsigned short* imgRow = imgT + l31;

  auto computeStep = [&](int buf, int ki){
    const char* bufp = ringb + buf * 4096;
    f32x16 S0 = {}, S1 = {}, S2 = {}, S3 = {};
    __builtin_amdgcn_s_setprio(1);
    #pragma unroll
    for (int cc = 0; cc < 4; ++cc){
      bf16x8 a = *(const bf16x8*)(bufp + aoff[cc]);
      S0 = mfma16(a, bfr[0][cc], S0);
      S1 = mfma16(a, bfr[1][cc], S1);
      S2 = mfma16(a, bfr[2][cc], S2);
      S3 = mfma16(a, bfr[3][cc], S3);
    }
    __builtin_amdgcn_s_setprio(0);
    float s0 = bf2f(imgRow[ki * 128]);
    float s1 = bf2f(imgRow[ki * 128 + 32]);
    float s2 = bf2f(imgRow[ki * 128 + 64]);
    float s3 = bf2f(imgRow[ki * 128 + 96]);
    acc[0] += S0 * s0; acc[1] += S1 * s1; acc[2] += S2 * s2; acc[3] += S3 * s3;
  };

  // main loop ki=0..61: prefetch ki+2, wait vmcnt(8) => buf ki complete
  int bcur = 0;
  for (int ki = 0; ki < 62; ++ki){
    int bpre = bcur + 2; if (bpre >= 3) bpre -= 3;
    STG(h * 64 + ki + 2, bpre);
    asm volatile("s_waitcnt vmcnt(8)" ::: "memory");
    computeStep(bcur, ki);
    bcur = (bcur == 2) ? 0 : bcur + 1;
  }
  // ki=62 (buf 2): h==0 prefetches bias step (idx 64 -> buf 1)
  if (h == 0){
    STG(128, 1);
    asm volatile("s_waitcnt vmcnt(8)" ::: "memory");   // {62,63,64} -> 62 done
  } else {
    asm volatile("s_waitcnt vmcnt(4)" ::: "memory");   // {62,63} -> 62 done
  }
  computeStep(2, 62);
  // ki=63 (buf 0)
  if (h == 0){
    asm volatile("s_waitcnt vmcnt(4)" ::: "memory");   // {63,64} -> 63 done
  } else {
    asm volatile("s_waitcnt vmcnt(0)" ::: "memory");
  }
  computeStep(0, 63);
  // bias step (h==0 only, buf 1): B = img frags, no scalar scale
  if (h == 0){
    asm volatile("s_waitcnt vmcnt(0)" ::: "memory");
    const char* bufp = ringb + 1 * 4096;
    #pragma unroll
    for (int cc = 0; cc < 4; ++cc){
      bf16x8 a = *(const bf16x8*)(bufp + aoff[cc]);
      #pragma unroll
      for (int f = 0; f < 4; ++f){
        bf16x8 bi = cvt8(&img[(size_t)(t0 + f * 32 + l31) * 128 + ch * 64 + cc * 16 + lg * 8]);
        acc[f] = mfma16(a, bi, acc[f]);
      }
    }
  }

  // ---- epilogue: combine c-halves in LDS, write partial coalesced ----
  __syncthreads();
  if (ch == 0){
    #pragma unroll
    for (int f = 0; f < 4; ++f){
      int t_l = f * 32 + l31;
      #pragma unroll
      for (int r = 0; r < 16; ++r){
        int p = pt * 32 + (r & 3) + 8 * (r >> 2) + 4 * lg;
        ldsY[t_l * 129 + p] = acc[f][r];
      }
    }
  }
  __syncthreads();
  if (ch == 1){
    #pragma unroll
    for (int f = 0; f < 4; ++f){
      int t_l = f * 32 + l31;
      #pragma unroll
      for (int r = 0; r < 16; ++r){
        int p = pt * 32 + (r & 3) + 8 * (r >> 2) + 4 * lg;
        ldsY[t_l * 129 + p] += acc[f][r];
      }
    }
  }
  __syncthreads();
  float* dst = part + ((size_t)h * 16384 + t0) * 128;
  #pragma unroll
  for (int k = 0; k < 8; ++k){
    int idx4 = k * 512 + tid;
    int t_l = idx4 >> 5, q = idx4 & 31;
    const float* s = &ldsY[t_l * 129 + q * 4];
    float4 v = {s[0], s[1], s[2], s[3]};
    *(float4*)&dst[t_l * 128 + q * 4] = v;
  }
}

// LN kernel: y = part0 + part1, LayerNorm + ReLU. grid 256 x 512 thr.
__global__ __launch_bounds__(512)
void lnk(const float* __restrict__ part, const float* __restrict__ gamma,
         const float* __restrict__ beta, float* __restrict__ out){
  const int tid = threadIdx.x, lane = tid & 63, wv = tid >> 6;
  const float* p0 = part;
  const float* p1 = part + (size_t)16384 * 128;
  float g0  = gamma[lane], g1 = gamma[lane + 64];
  float be0 = beta[lane],  be1 = beta[lane + 64];
  int tb = blockIdx.x * 64 + wv * 8;
  #pragma unroll 1
  for (int k = 0; k < 8; ++k){
    size_t t = tb + k;
    float y0 = p0[t * 128 + lane]      + p1[t * 128 + lane];
    float y1 = p0[t * 128 + 64 + lane] + p1[t * 128 + 64 + lane];
    float s = y0 + y1, sq = y0 * y0 + y1 * y1;
    #pragma unroll
    for (int m = 32; m >= 1; m >>= 1){
      s  += __shfl_xor(s, m, 64);
      sq += __shfl_xor(sq, m, 64);
    }
    float mean = s * (1.0f / 128.0f);
    float var  = sq * (1.0f / 128.0f) - mean * mean;
    float rs   = rsqrtf(var + 1e-5f);
    float o0 = fmaxf((y0 - mean) * rs * g0 + be0, 0.0f);
    float o1 = fmaxf((y1 - mean) * rs * g1 + be1, 0.0f);
    out[t * 128 + lane]      = o0;
    out[t * 128 + 64 + lane] = o1;
  }
}

extern "C" void kernel_launch(void* const* d_in, const int* in_sizes, int n_in,
                              void* d_out, int out_size, void* d_ws, size_t ws_size,
                              hipStream_t stream){
  const float* img   = (const float*)d_in[0];
  const float* loc   = (const float*)d_in[1];
  const float* W     = (const float*)d_in[2];
  const float* bias  = (const float*)d_in[3];
  const float* gamma = (const float*)d_in[4];
  const float* beta  = (const float*)d_in[5];
  float* out = (float*)d_out;
  unsigned short* Wb2 = (unsigned short*)d_ws;                 // 4,227,072 B
  float* part = (float*)((char*)d_ws + 4227072);               // 2 x 16384 x 128 f32 = 16 MB

  prep_wb2<<<8256, 256, 0, stream>>>(W, bias, Wb2);
  dynmlp<<<256, 512, 0, stream>>>(img, loc, Wb2, part);
  lnk<<<256, 512, 0, stream>>>(part, gamma, beta, out);
}